// Round 1
// baseline (376.029 us; speedup 1.0000x reference)
//
#include <hip/hip_runtime.h>

// Problem: B=8192, L=64, M=64, LOCAL_DIM=4, eps shape (4, 64, 64, 65, 65) f32.
// out[b] = sum_m prod_l eps[idx[b,l], m, l, nup[b,l], ndn[b,l]]
// nup/ndn = exclusive cumsum of bit0/bit1 of idx along l.
//
// eps element strides: d:17305600, m:270400, l:4225, u:65, n:1
// Compact transposed table (only reachable u<=l, n<=l states):
//   tab[(P_l + u*(l+1) + n)*256 + d*64 + m],  P_l = l(l+1)(2l+1)/6
// total = 89440 * 256 floats = 91,586,560 bytes

#define TAB_BYTES ((size_t)89440 * 256 * 4)

__global__ __launch_bounds__(256) void seggps_transpose(
    const float* __restrict__ eps, float* __restrict__ tab) {
  int bid = blockIdx.x;                 // grid = 65*64*4 = 16640
  int u = bid % 65;
  int l = (bid / 65) & 63;
  int d = bid / (65 * 64);
  if (u > l) return;                    // unreachable state, nothing to copy

  int lane = threadIdx.x & 63;          // n on load, m on store
  int wave = threadIdx.x >> 6;          // 4 waves

  __shared__ float tile[64][65];        // [m][n], stride 65 -> 2-way LDS alias (free)

  // load: coalesced along n (stride 1 in eps)
  const float* src = eps + ((size_t)(d * 64) * 64 + l) * 4225 + u * 65;
  if (lane <= l) {
    for (int m = wave; m < 64; m += 4) {
      tile[m][lane] = src[(size_t)m * 270400 + lane];
    }
  }
  __syncthreads();

  // store: coalesced along m (stride 1 in tab)
  int Pl = l * (l + 1) * (2 * l + 1) / 6;
  float* dst = tab + (size_t)(Pl + u * (l + 1)) * 256 + d * 64 + lane;
  for (int n = wave; n <= l; n += 4) {
    dst[n * 256] = tile[lane][n];
  }
}

__global__ __launch_bounds__(256) void seggps_main(
    const int* __restrict__ indices, const float* __restrict__ tab,
    float* __restrict__ out) {
  int wave = threadIdx.x >> 6;
  int lane = threadIdx.x & 63;          // lane = m
  int b = blockIdx.x * 4 + wave;

  int myidx = indices[b * 64 + lane];   // lane l's site value, broadcast later

  float p0 = 1.f, p1 = 1.f, p2 = 1.f, p3 = 1.f;
  int up = 0, dn = 0;
#pragma unroll
  for (int l = 0; l < 64; ++l) {
    int v = __shfl(myidx, l, 64);
    int Pl = l * (l + 1) * (2 * l + 1) / 6;    // constant-folds under unroll
    int off = (Pl + up * (l + 1) + dn) * 256 + v * 64 + lane;
    float e = tab[off];                        // 256B coalesced per wave
    if ((l & 3) == 0)      p0 *= e;
    else if ((l & 3) == 1) p1 *= e;
    else if ((l & 3) == 2) p2 *= e;
    else                   p3 *= e;
    up += v & 1;
    dn += (v >> 1) & 1;
  }
  float p = (p0 * p1) * (p2 * p3);
#pragma unroll
  for (int s = 32; s; s >>= 1) p += __shfl_down(p, s, 64);
  if (lane == 0) out[b] = p;
}

// Fallback if workspace is too small: gather straight from eps (uncoalesced
// along m, slower, but correct).
__global__ __launch_bounds__(256) void seggps_direct(
    const int* __restrict__ indices, const float* __restrict__ eps,
    float* __restrict__ out) {
  int wave = threadIdx.x >> 6;
  int lane = threadIdx.x & 63;          // lane = m
  int b = blockIdx.x * 4 + wave;

  int myidx = indices[b * 64 + lane];

  float p0 = 1.f, p1 = 1.f, p2 = 1.f, p3 = 1.f;
  int up = 0, dn = 0;
#pragma unroll 8
  for (int l = 0; l < 64; ++l) {
    int v = __shfl(myidx, l, 64);
    size_t off = ((size_t)((v * 64 + lane) * 64 + l)) * 4225 + up * 65 + dn;
    float e = eps[off];
    if ((l & 3) == 0)      p0 *= e;
    else if ((l & 3) == 1) p1 *= e;
    else if ((l & 3) == 2) p2 *= e;
    else                   p3 *= e;
    up += v & 1;
    dn += (v >> 1) & 1;
  }
  float p = (p0 * p1) * (p2 * p3);
#pragma unroll
  for (int s = 32; s; s >>= 1) p += __shfl_down(p, s, 64);
  if (lane == 0) out[b] = p;
}

extern "C" void kernel_launch(void* const* d_in, const int* in_sizes, int n_in,
                              void* d_out, int out_size, void* d_ws, size_t ws_size,
                              hipStream_t stream) {
  const int* indices = (const int*)d_in[0];   // (8192, 64) int
  const float* eps   = (const float*)d_in[1]; // (4, 64, 64, 65, 65) f32
  float* out = (float*)d_out;                 // (8192,) f32

  if (ws_size >= TAB_BYTES) {
    float* tab = (float*)d_ws;
    hipLaunchKernelGGL(seggps_transpose, dim3(65 * 64 * 4), dim3(256), 0, stream,
                       eps, tab);
    hipLaunchKernelGGL(seggps_main, dim3(8192 / 4), dim3(256), 0, stream,
                       indices, tab, out);
  } else {
    hipLaunchKernelGGL(seggps_direct, dim3(8192 / 4), dim3(256), 0, stream,
                       indices, eps, out);
  }
}

// Round 2
// 365.759 us; speedup vs baseline: 1.0281x; 1.0281x over previous
//
#include <hip/hip_runtime.h>

// Problem: B=8192, L=64, M=64, LOCAL_DIM=4, eps shape (4, 64, 64, 65, 65) f32.
// out[b] = sum_m prod_l eps[idx[b,l], m, l, nup[b,l], ndn[b,l]]
// nup/ndn = exclusive cumsum of bit0/bit1 of idx along l.
//
// eps element strides: d:17305600, m:270400, l:4225, u:65, n:1
// Compact transposed table (only reachable u<=l, n<=l states):
//   tab[(P_l + u*(l+1) + n)*256 + d*64 + m],  P_l = l(l+1)(2l+1)/6
// total = 89440 * 256 floats = 91,586,560 bytes

#define TAB_BYTES ((size_t)89440 * 256 * 4)

__global__ __launch_bounds__(256) void seggps_transpose(
    const float* __restrict__ eps, float* __restrict__ tab) {
  int bid = blockIdx.x;                 // grid = 4 * 2080 (triangular, no dead blocks)
  int d = bid / 2080;
  int t = bid % 2080;
  int l = (int)((sqrtf(8.0f * (float)t + 1.0f) - 1.0f) * 0.5f);
  while ((l + 1) * (l + 2) / 2 <= t) ++l;   // fix fp rounding
  while (l * (l + 1) / 2 > t) --l;
  int u = t - l * (l + 1) / 2;

  int lane = threadIdx.x & 63;          // n on load, m on store
  int wave = threadIdx.x >> 6;          // 4 waves

  __shared__ float tile[64][65];        // [m][n], stride 65 -> 2-way LDS alias (free)

  // load: coalesced along n (stride 1 in eps)
  const float* src = eps + ((size_t)(d * 64) * 64 + l) * 4225 + u * 65;
  if (lane <= l) {
#pragma unroll 4
    for (int m = wave; m < 64; m += 4) {
      tile[m][lane] = src[(size_t)m * 270400 + lane];
    }
  }
  __syncthreads();

  // store: coalesced along m (stride 1 in tab)
  int Pl = l * (l + 1) * (2 * l + 1) / 6;
  float* dst = tab + (size_t)(Pl + u * (l + 1)) * 256 + d * 64 + lane;
#pragma unroll 4
  for (int n = wave; n <= l; n += 4) {
    dst[n * 256] = tile[lane][n];
  }
}

// 2 batches per wave: two independent gather/product chains double MLP per
// wave; unroll 16 keeps VGPR in check; launch_bounds(256,4) -> <=128 VGPR,
// 16 waves/CU.
__global__ __launch_bounds__(256, 4) void seggps_main(
    const int* __restrict__ indices, const float* __restrict__ tab,
    float* __restrict__ out) {
  int wave = threadIdx.x >> 6;
  int lane = threadIdx.x & 63;          // lane = m
  int b0 = (blockIdx.x * 4 + wave) * 2; // this wave handles b0, b0+1

  int i0 = indices[b0 * 64 + lane];
  int i1 = indices[b0 * 64 + 64 + lane];

  float pa0 = 1.f, pb0 = 1.f, pa1 = 1.f, pb1 = 1.f;
  int up0 = 0, dn0 = 0, up1 = 0, dn1 = 0;
  int Pl = 0;                           // l(l+1)(2l+1)/6, built incrementally
#pragma unroll 16
  for (int l = 0; l < 64; ++l) {
    int v0 = __shfl(i0, l, 64);
    int v1 = __shfl(i1, l, 64);
    int base = Pl * 256 + lane;
    int o0 = base + (up0 * (l + 1) + dn0) * 256 + v0 * 64;
    int o1 = base + (up1 * (l + 1) + dn1) * 256 + v1 * 64;
    float e0 = tab[o0];                 // 256B coalesced per wave
    float e1 = tab[o1];
    if (l & 1) { pa0 *= e0; pa1 *= e1; }
    else       { pb0 *= e0; pb1 *= e1; }
    up0 += v0 & 1;  dn0 += (v0 >> 1) & 1;
    up1 += v1 & 1;  dn1 += (v1 >> 1) & 1;
    Pl += (l + 1) * (l + 1);
  }
  float p0 = pa0 * pb0;
  float p1 = pa1 * pb1;
#pragma unroll
  for (int s = 32; s; s >>= 1) {
    p0 += __shfl_down(p0, s, 64);
    p1 += __shfl_down(p1, s, 64);
  }
  if (lane == 0) {
    out[b0] = p0;
    out[b0 + 1] = p1;
  }
}

// Fallback if workspace is too small: gather straight from eps (uncoalesced
// along m, slower, but correct).
__global__ __launch_bounds__(256) void seggps_direct(
    const int* __restrict__ indices, const float* __restrict__ eps,
    float* __restrict__ out) {
  int wave = threadIdx.x >> 6;
  int lane = threadIdx.x & 63;          // lane = m
  int b = blockIdx.x * 4 + wave;

  int myidx = indices[b * 64 + lane];

  float p0 = 1.f, p1 = 1.f, p2 = 1.f, p3 = 1.f;
  int up = 0, dn = 0;
#pragma unroll 8
  for (int l = 0; l < 64; ++l) {
    int v = __shfl(myidx, l, 64);
    size_t off = ((size_t)((v * 64 + lane) * 64 + l)) * 4225 + up * 65 + dn;
    float e = eps[off];
    if ((l & 3) == 0)      p0 *= e;
    else if ((l & 3) == 1) p1 *= e;
    else if ((l & 3) == 2) p2 *= e;
    else                   p3 *= e;
    up += v & 1;
    dn += (v >> 1) & 1;
  }
  float p = (p0 * p1) * (p2 * p3);
#pragma unroll
  for (int s = 32; s; s >>= 1) p += __shfl_down(p, s, 64);
  if (lane == 0) out[b] = p;
}

extern "C" void kernel_launch(void* const* d_in, const int* in_sizes, int n_in,
                              void* d_out, int out_size, void* d_ws, size_t ws_size,
                              hipStream_t stream) {
  const int* indices = (const int*)d_in[0];   // (8192, 64) int
  const float* eps   = (const float*)d_in[1]; // (4, 64, 64, 65, 65) f32
  float* out = (float*)d_out;                 // (8192,) f32

  if (ws_size >= TAB_BYTES) {
    float* tab = (float*)d_ws;
    hipLaunchKernelGGL(seggps_transpose, dim3(4 * 2080), dim3(256), 0, stream,
                       eps, tab);
    hipLaunchKernelGGL(seggps_main, dim3(8192 / 8), dim3(256), 0, stream,
                       indices, tab, out);
  } else {
    hipLaunchKernelGGL(seggps_direct, dim3(8192 / 4), dim3(256), 0, stream,
                       indices, eps, out);
  }
}

// Round 3
// 354.523 us; speedup vs baseline: 1.0607x; 1.0317x over previous
//
#include <hip/hip_runtime.h>
#include <hip/hip_fp16.h>

// Problem: B=8192, L=64, M=64, LOCAL_DIM=4, eps shape (4, 64, 64, 65, 65) f32.
// out[b] = sum_m prod_l eps[idx[b,l], m, l, nup[b,l], ndn[b,l]]
// nup/ndn = exclusive cumsum of bit0/bit1 of idx along l.
//
// eps element strides: d:17305600, m:270400, l:4225, u:65, n:1
// Compact transposed table (only reachable u<=l, n<=l states), fp16:
//   tab[(P_l + u*(l+1) + n)*256 + d*64 + m],  P_l = l(l+1)(2l+1)/6
// total = 89440 * 256 halfs = 45.8 MB
// fp16 accuracy: eps in ~[0.7,1.3]; rel err <= 4.9e-4/elem; product of 64
// -> ~2.3e-3 RMS rel; out ~70 -> abs err ~0.1 << 1.56 threshold.

#define TAB_HALF_BYTES ((size_t)89440 * 256 * 2)

__global__ __launch_bounds__(256) void seggps_transpose(
    const float* __restrict__ eps, __half* __restrict__ tab) {
  int bid = blockIdx.x;                 // grid = 4 * 2080 (triangular, no dead blocks)
  int d = bid / 2080;
  int t = bid % 2080;
  int l = (int)((sqrtf(8.0f * (float)t + 1.0f) - 1.0f) * 0.5f);
  while ((l + 1) * (l + 2) / 2 <= t) ++l;   // fix fp rounding
  while (l * (l + 1) / 2 > t) --l;
  int u = t - l * (l + 1) / 2;

  int lane = threadIdx.x & 63;          // n on load, m on store
  int wave = threadIdx.x >> 6;          // 4 waves

  __shared__ float tile[64][65];        // [m][n], stride 65 -> 2-way LDS alias (free)

  // load: coalesced along n (stride 1 in eps); nontemporal (eps never reused)
  const float* src = eps + ((size_t)(d * 64) * 64 + l) * 4225 + u * 65;
  if (lane <= l) {
#pragma unroll 4
    for (int m = wave; m < 64; m += 4) {
      tile[m][lane] = __builtin_nontemporal_load(&src[(size_t)m * 270400 + lane]);
    }
  }
  __syncthreads();

  // store: coalesced along m (stride 1 in tab), 128B contiguous per wave
  int Pl = l * (l + 1) * (2 * l + 1) / 6;
  __half* dst = tab + (size_t)(Pl + u * (l + 1)) * 256 + d * 64 + lane;
#pragma unroll 4
  for (int n = wave; n <= l; n += 4) {
    dst[n * 256] = __float2half(tile[lane][n]);
  }
}

// 2 batches per wave: two independent gather/product chains double MLP per
// wave; launch_bounds(256,4) -> <=128 VGPR, 16 waves/CU.
__global__ __launch_bounds__(256, 4) void seggps_main(
    const int* __restrict__ indices, const __half* __restrict__ tab,
    float* __restrict__ out) {
  int wave = threadIdx.x >> 6;
  int lane = threadIdx.x & 63;          // lane = m
  int b0 = (blockIdx.x * 4 + wave) * 2; // this wave handles b0, b0+1

  int i0 = indices[b0 * 64 + lane];
  int i1 = indices[b0 * 64 + 64 + lane];

  float pa0 = 1.f, pb0 = 1.f, pa1 = 1.f, pb1 = 1.f;
  int up0 = 0, dn0 = 0, up1 = 0, dn1 = 0;
  int Pl = 0;                           // l(l+1)(2l+1)/6, built incrementally
#pragma unroll 16
  for (int l = 0; l < 64; ++l) {
    int v0 = __shfl(i0, l, 64);
    int v1 = __shfl(i1, l, 64);
    int base = Pl * 256 + lane;
    int o0 = base + (up0 * (l + 1) + dn0) * 256 + v0 * 64;
    int o1 = base + (up1 * (l + 1) + dn1) * 256 + v1 * 64;
    float e0 = __half2float(tab[o0]);   // 128B contiguous per wave
    float e1 = __half2float(tab[o1]);
    if (l & 1) { pa0 *= e0; pa1 *= e1; }
    else       { pb0 *= e0; pb1 *= e1; }
    up0 += v0 & 1;  dn0 += (v0 >> 1) & 1;
    up1 += v1 & 1;  dn1 += (v1 >> 1) & 1;
    Pl += (l + 1) * (l + 1);
  }
  float p0 = pa0 * pb0;
  float p1 = pa1 * pb1;
#pragma unroll
  for (int s = 32; s; s >>= 1) {
    p0 += __shfl_down(p0, s, 64);
    p1 += __shfl_down(p1, s, 64);
  }
  if (lane == 0) {
    out[b0] = p0;
    out[b0 + 1] = p1;
  }
}

// Fallback if workspace is too small: gather straight from eps (uncoalesced
// along m, slower, but correct).
__global__ __launch_bounds__(256) void seggps_direct(
    const int* __restrict__ indices, const float* __restrict__ eps,
    float* __restrict__ out) {
  int wave = threadIdx.x >> 6;
  int lane = threadIdx.x & 63;          // lane = m
  int b = blockIdx.x * 4 + wave;

  int myidx = indices[b * 64 + lane];

  float p0 = 1.f, p1 = 1.f, p2 = 1.f, p3 = 1.f;
  int up = 0, dn = 0;
#pragma unroll 8
  for (int l = 0; l < 64; ++l) {
    int v = __shfl(myidx, l, 64);
    size_t off = ((size_t)((v * 64 + lane) * 64 + l)) * 4225 + up * 65 + dn;
    float e = eps[off];
    if ((l & 3) == 0)      p0 *= e;
    else if ((l & 3) == 1) p1 *= e;
    else if ((l & 3) == 2) p2 *= e;
    else                   p3 *= e;
    up += v & 1;
    dn += (v >> 1) & 1;
  }
  float p = (p0 * p1) * (p2 * p3);
#pragma unroll
  for (int s = 32; s; s >>= 1) p += __shfl_down(p, s, 64);
  if (lane == 0) out[b] = p;
}

extern "C" void kernel_launch(void* const* d_in, const int* in_sizes, int n_in,
                              void* d_out, int out_size, void* d_ws, size_t ws_size,
                              hipStream_t stream) {
  const int* indices = (const int*)d_in[0];   // (8192, 64) int
  const float* eps   = (const float*)d_in[1]; // (4, 64, 64, 65, 65) f32
  float* out = (float*)d_out;                 // (8192,) f32

  if (ws_size >= TAB_HALF_BYTES) {
    __half* tab = (__half*)d_ws;
    hipLaunchKernelGGL(seggps_transpose, dim3(4 * 2080), dim3(256), 0, stream,
                       eps, tab);
    hipLaunchKernelGGL(seggps_main, dim3(8192 / 8), dim3(256), 0, stream,
                       indices, tab, out);
  } else {
    hipLaunchKernelGGL(seggps_direct, dim3(8192 / 4), dim3(256), 0, stream,
                       indices, eps, out);
  }
}

// Round 4
// 347.803 us; speedup vs baseline: 1.0812x; 1.0193x over previous
//
#include <hip/hip_runtime.h>
#include <hip/hip_fp16.h>

// Problem: B=8192, L=64, M=64, LOCAL_DIM=4, eps shape (4, 64, 64, 65, 65) f32.
// out[b] = sum_m prod_l eps[idx[b,l], m, l, nup[b,l], ndn[b,l]]
// nup/ndn = exclusive cumsum of bit0/bit1 of idx along l.
//
// eps element strides: d:17305600, m:270400, l:4225, u:65, n:1
// Compact transposed table (reachable u<=l, n<=l states), fp16:
//   tab[(P_l + u*(l+1) + n)*256 + d*64 + m],  P_l = l(l+1)(2l+1)/6
// fp16 accuracy: eps ~[0.7,1.3]; product-of-64 rel err ~2.3e-3; absmax 0.5
// observed vs 1.56 threshold.
//
// R4: only transpose states actually VISITED by this batch. u,n ~
// Binomial(l,1/2) -> visited box per l is ~7*sqrt(l)/2 wide; pre-pass
// computes per-l [umin,umax]x[nmin,nmax], transpose skips the rest.
// Main kernel reads only visited states, so unfilled tab entries are
// never touched. ~3.5x less transpose traffic.

#define TAB_HALF_BYTES ((size_t)89440 * 256 * 2)

__global__ __launch_bounds__(256) void seggps_init(int* __restrict__ ranges) {
  int t = threadIdx.x;
  if (t < 64) {
    ranges[t] = 64;        // umin
    ranges[64 + t] = -1;   // umax
    ranges[128 + t] = 64;  // nmin
    ranges[192 + t] = -1;  // nmax
  }
}

// grid = 128 blocks x 256 thr; block handles 64 batches. Wave prefix-scan
// gives each batch's (u,n) at every l; LDS min/max then 256 global atomics.
__global__ __launch_bounds__(256) void seggps_ranges(
    const int* __restrict__ indices, int* __restrict__ ranges) {
  __shared__ int s_umin[64], s_umax[64], s_nmin[64], s_nmax[64];
  int t = threadIdx.x;
  if (t < 64) { s_umin[t] = 64; s_umax[t] = -1; s_nmin[t] = 64; s_nmax[t] = -1; }
  __syncthreads();
  int wave = t >> 6, lane = t & 63;    // lane = l
  for (int i = 0; i < 16; ++i) {
    int b = blockIdx.x * 64 + wave * 16 + i;
    int v = indices[b * 64 + lane];
    int up = v & 1, dn = (v >> 1) & 1;
#pragma unroll
    for (int s = 1; s < 64; s <<= 1) { // inclusive scan across lanes
      int au = __shfl_up(up, s, 64);
      int ad = __shfl_up(dn, s, 64);
      if (lane >= s) { up += au; dn += ad; }
    }
    int eu = up - (v & 1);             // exclusive
    int ed = dn - ((v >> 1) & 1);
    atomicMin(&s_umin[lane], eu); atomicMax(&s_umax[lane], eu);
    atomicMin(&s_nmin[lane], ed); atomicMax(&s_nmax[lane], ed);
  }
  __syncthreads();
  if (t < 64) {
    atomicMin(&ranges[t], s_umin[t]);
    atomicMax(&ranges[64 + t], s_umax[t]);
    atomicMin(&ranges[128 + t], s_nmin[t]);
    atomicMax(&ranges[192 + t], s_nmax[t]);
  }
}

__global__ __launch_bounds__(256) void seggps_transpose(
    const float* __restrict__ eps, __half* __restrict__ tab,
    const int* __restrict__ ranges) {
  int bid = blockIdx.x;                 // grid = 4 * 2080 (triangular)
  int d = bid / 2080;
  int t = bid % 2080;
  int l = (int)((sqrtf(8.0f * (float)t + 1.0f) - 1.0f) * 0.5f);
  while ((l + 1) * (l + 2) / 2 <= t) ++l;   // fix fp rounding
  while (l * (l + 1) / 2 > t) --l;
  int u = t - l * (l + 1) / 2;

  int umin = ranges[l], umax = ranges[64 + l];
  if (u < umin || u > umax) return;     // no batch visits this u at site l
  int nmin = ranges[128 + l], nmax = ranges[192 + l];  // nmax <= l always

  int lane = threadIdx.x & 63;          // n on load, m on store
  int wave = threadIdx.x >> 6;          // 4 waves

  __shared__ float tile[64][65];        // [m][n]

  // load: coalesced along n (stride 1 in eps); nontemporal (no reuse)
  const float* src = eps + ((size_t)(d * 64) * 64 + l) * 4225 + u * 65;
  if (lane >= nmin && lane <= nmax) {
#pragma unroll 4
    for (int m = wave; m < 64; m += 4) {
      tile[m][lane] = __builtin_nontemporal_load(&src[(size_t)m * 270400 + lane]);
    }
  }
  __syncthreads();

  // store: coalesced along m (128B contiguous per wave)
  int Pl = l * (l + 1) * (2 * l + 1) / 6;
  __half* dst = tab + (size_t)(Pl + u * (l + 1)) * 256 + d * 64 + lane;
  for (int n = nmin + wave; n <= nmax; n += 4) {
    dst[n * 256] = __float2half(tile[lane][n]);
  }
}

// 2 batches per wave: two independent gather/product chains double MLP per
// wave; launch_bounds(256,4) -> <=128 VGPR, 16 waves/CU.
__global__ __launch_bounds__(256, 4) void seggps_main(
    const int* __restrict__ indices, const __half* __restrict__ tab,
    float* __restrict__ out) {
  int wave = threadIdx.x >> 6;
  int lane = threadIdx.x & 63;          // lane = m
  int b0 = (blockIdx.x * 4 + wave) * 2; // this wave handles b0, b0+1

  int i0 = indices[b0 * 64 + lane];
  int i1 = indices[b0 * 64 + 64 + lane];

  float pa0 = 1.f, pb0 = 1.f, pa1 = 1.f, pb1 = 1.f;
  int up0 = 0, dn0 = 0, up1 = 0, dn1 = 0;
  int Pl = 0;                           // l(l+1)(2l+1)/6, built incrementally
#pragma unroll 16
  for (int l = 0; l < 64; ++l) {
    int v0 = __shfl(i0, l, 64);
    int v1 = __shfl(i1, l, 64);
    int base = Pl * 256 + lane;
    int o0 = base + (up0 * (l + 1) + dn0) * 256 + v0 * 64;
    int o1 = base + (up1 * (l + 1) + dn1) * 256 + v1 * 64;
    float e0 = __half2float(tab[o0]);   // 128B contiguous per wave
    float e1 = __half2float(tab[o1]);
    if (l & 1) { pa0 *= e0; pa1 *= e1; }
    else       { pb0 *= e0; pb1 *= e1; }
    up0 += v0 & 1;  dn0 += (v0 >> 1) & 1;
    up1 += v1 & 1;  dn1 += (v1 >> 1) & 1;
    Pl += (l + 1) * (l + 1);
  }
  float p0 = pa0 * pb0;
  float p1 = pa1 * pb1;
#pragma unroll
  for (int s = 32; s; s >>= 1) {
    p0 += __shfl_down(p0, s, 64);
    p1 += __shfl_down(p1, s, 64);
  }
  if (lane == 0) {
    out[b0] = p0;
    out[b0 + 1] = p1;
  }
}

// Fallback if workspace is too small: gather straight from eps.
__global__ __launch_bounds__(256) void seggps_direct(
    const int* __restrict__ indices, const float* __restrict__ eps,
    float* __restrict__ out) {
  int wave = threadIdx.x >> 6;
  int lane = threadIdx.x & 63;          // lane = m
  int b = blockIdx.x * 4 + wave;

  int myidx = indices[b * 64 + lane];

  float p0 = 1.f, p1 = 1.f, p2 = 1.f, p3 = 1.f;
  int up = 0, dn = 0;
#pragma unroll 8
  for (int l = 0; l < 64; ++l) {
    int v = __shfl(myidx, l, 64);
    size_t off = ((size_t)((v * 64 + lane) * 64 + l)) * 4225 + up * 65 + dn;
    float e = eps[off];
    if ((l & 3) == 0)      p0 *= e;
    else if ((l & 3) == 1) p1 *= e;
    else if ((l & 3) == 2) p2 *= e;
    else                   p3 *= e;
    up += v & 1;
    dn += (v >> 1) & 1;
  }
  float p = (p0 * p1) * (p2 * p3);
#pragma unroll
  for (int s = 32; s; s >>= 1) p += __shfl_down(p, s, 64);
  if (lane == 0) out[b] = p;
}

extern "C" void kernel_launch(void* const* d_in, const int* in_sizes, int n_in,
                              void* d_out, int out_size, void* d_ws, size_t ws_size,
                              hipStream_t stream) {
  const int* indices = (const int*)d_in[0];   // (8192, 64) int
  const float* eps   = (const float*)d_in[1]; // (4, 64, 64, 65, 65) f32
  float* out = (float*)d_out;                 // (8192,) f32

  if (ws_size >= TAB_HALF_BYTES + 1024) {
    __half* tab = (__half*)d_ws;
    int* ranges = (int*)((char*)d_ws + TAB_HALF_BYTES);  // 256 ints
    hipLaunchKernelGGL(seggps_init, dim3(1), dim3(256), 0, stream, ranges);
    hipLaunchKernelGGL(seggps_ranges, dim3(128), dim3(256), 0, stream,
                       indices, ranges);
    hipLaunchKernelGGL(seggps_transpose, dim3(4 * 2080), dim3(256), 0, stream,
                       eps, tab, ranges);
    hipLaunchKernelGGL(seggps_main, dim3(8192 / 8), dim3(256), 0, stream,
                       indices, tab, out);
  } else {
    hipLaunchKernelGGL(seggps_direct, dim3(8192 / 4), dim3(256), 0, stream,
                       indices, eps, out);
  }
}